// Round 1
// baseline (442.212 us; speedup 1.0000x reference)
//
#include <hip/hip_runtime.h>
#include <hip/hip_bf16.h>

#define LDIM 64
#define CDIM 128

static __device__ __forceinline__ unsigned short f2bf(float f) {
    unsigned int x = __float_as_uint(f);
    unsigned int r = (x + 0x7fffu + ((x >> 16) & 1u)) >> 16;
    return (unsigned short)r;
}
static __device__ __forceinline__ float bf2f(unsigned int u) {
    return __uint_as_float(u << 16);
}

// ---- counts = bincount(local_cellxgene_ix) ----
__global__ __launch_bounds__(256) void hist_kernel(const int* __restrict__ idx, int n,
                                                   unsigned int* __restrict__ counts) {
    int i = blockIdx.x * blockDim.x + threadIdx.x;
    int stride = gridDim.x * blockDim.x;
    for (; i < n; i += stride) atomicAdd(&counts[idx[i]], 1u);
}

// ---- Poisson part: sum over all (b,g) pairs ----
__global__ __launch_bounds__(256) void poisson_kernel(
    const float* __restrict__ latent, const int* __restrict__ genes_oi,
    const int* __restrict__ cells_oi, const float* __restrict__ rho_weight,
    const float* __restrict__ rho_bias, const int* __restrict__ libsize,
    const unsigned int* __restrict__ counts, int B, int G, float* __restrict__ out) {
    int total = B * G;
    float acc = 0.f;
    for (int i = blockIdx.x * blockDim.x + threadIdx.x; i < total;
         i += gridDim.x * blockDim.x) {
        int b = i / G;
        int g = i - b * G;
        int gene = genes_oi[g];
        const float4* la = (const float4*)(latent + (size_t)b * LDIM);
        const float4* rw = (const float4*)(rho_weight + (size_t)gene * LDIM);
        float d = 0.f;
        #pragma unroll
        for (int k = 0; k < LDIM / 4; ++k) {
            float4 a = la[k], w = rw[k];
            d += a.x * w.x + a.y * w.y + a.z * w.z + a.w * w.w;
        }
        float lib = (float)libsize[cells_oi[b]];
        float rate = rho_bias[gene] * __expf(d) * lib;
        unsigned int c = counts[i];
        float lgam = 0.f;
        for (unsigned int k = 2; k <= c; ++k) lgam += __logf((float)k);
        acc += (float)c * __logf(rate) - rate - lgam;
    }
    #pragma unroll
    for (int o = 32; o; o >>= 1) acc += __shfl_xor(acc, o);
    if ((threadIdx.x & 63) == 0) atomicAdd(out, -acc);
}

// ---- mixture_delta GEMM: per gene, 64-cell tile; stores bf16 chunk ----
__global__ __launch_bounds__(256) void delta_gemm_kernel(
    const float* __restrict__ latent, const int* __restrict__ genes_oi,
    const float* __restrict__ logit_weight, unsigned short* __restrict__ delta,
    int G, int b0, int CBc) {
    __shared__ float lw_s[LDIM][CDIM];       // 32 KB
    __shared__ float lat_s[64][LDIM + 4];    // 17 KB, padded stride (bank spread)
    int g = blockIdx.x;
    int t = threadIdx.x;
    int row0 = blockIdx.y * 64;
    int gene = genes_oi[g];

    // stage logit_weight[gene] (64x128 f32, contiguous) via float4
    const float4* src = (const float4*)(logit_weight + (size_t)gene * LDIM * CDIM);
    float4* dst = (float4*)(&lw_s[0][0]);
    #pragma unroll
    for (int k = 0; k < (LDIM * CDIM / 4) / 256; ++k) dst[t + k * 256] = src[t + k * 256];

    // stage 64 cells of latent (zero-pad beyond chunk)
    for (int idx = t; idx < 64 * (LDIM / 4); idx += 256) {
        int r = idx >> 4;   // LDIM/4 == 16
        int k = idx & 15;
        float4 v = make_float4(0.f, 0.f, 0.f, 0.f);
        if (row0 + r < CBc)
            v = ((const float4*)(latent + (size_t)(b0 + row0 + r) * LDIM))[k];
        ((float4*)(&lat_s[r][0]))[k] = v;
    }
    __syncthreads();

    int cg = t >> 4;   // 16 cell-groups x 4 cells
    int qc = t & 15;   // 16 c-groups x 8 cols
    float acc[4][8];
    #pragma unroll
    for (int i = 0; i < 4; ++i)
        #pragma unroll
        for (int j = 0; j < 8; ++j) acc[i][j] = 0.f;

    #pragma unroll 4
    for (int l = 0; l < LDIM; ++l) {
        const float4* wr = (const float4*)(&lw_s[l][0]);
        float4 w0 = wr[qc * 2];
        float4 w1 = wr[qc * 2 + 1];
        #pragma unroll
        for (int i = 0; i < 4; ++i) {
            float a = lat_s[cg * 4 + i][l];
            acc[i][0] += a * w0.x; acc[i][1] += a * w0.y;
            acc[i][2] += a * w0.z; acc[i][3] += a * w0.w;
            acc[i][4] += a * w1.x; acc[i][5] += a * w1.y;
            acc[i][6] += a * w1.z; acc[i][7] += a * w1.w;
        }
    }

    #pragma unroll
    for (int i = 0; i < 4; ++i) {
        int rloc = row0 + cg * 4 + i;
        if (rloc < CBc) {
            union { unsigned short u[8]; uint4 v; } pk;
            #pragma unroll
            for (int j = 0; j < 8; ++j) pk.u[j] = f2bf(acc[i][j]);
            *((uint4*)(delta + ((size_t)rloc * G + g) * CDIM + qc * 8)) = pk.v;
        }
    }
}

// ---- mixture likelihood: one wave per cut, 2 bins per lane ----
__global__ __launch_bounds__(256) void mixture_kernel(
    const int* __restrict__ cut_pair, const int* __restrict__ cut_gene,
    const float* __restrict__ cut_coord, const int* __restrict__ genes_oi,
    const float* __restrict__ spline_heights, const unsigned short* __restrict__ delta,
    int p0, int p1, int ncuts, float* __restrict__ out) {
    int wid = (blockIdx.x * blockDim.x + threadIdx.x) >> 6;
    int lane = threadIdx.x & 63;
    int nw = (gridDim.x * blockDim.x) >> 6;
    float acc = 0.f;
    for (int cut = wid; cut < ncuts; cut += nw) {
        int p = cut_pair[cut];
        if (p < p0 || p >= p1) continue;   // wave-uniform skip (multi-pass mode)
        int gene = genes_oi[cut_gene[cut]];
        float2 hv = ((const float2*)(spline_heights + (size_t)gene * CDIM))[lane];
        unsigned int dv = ((const unsigned int*)(delta + (size_t)(p - p0) * CDIM))[lane];
        float h0 = hv.x + bf2f(dv & 0xffffu);
        float h1 = hv.y + bf2f(dv >> 16);
        float m = fmaxf(h0, h1);
        #pragma unroll
        for (int o = 32; o; o >>= 1) m = fmaxf(m, __shfl_xor(m, o));
        float s = __expf(h0 - m) + __expf(h1 - m);
        #pragma unroll
        for (int o = 32; o; o >>= 1) s += __shfl_xor(s, o);
        float lse = m + __logf(s);
        int bin = (int)(cut_coord[cut] * 128.0f);
        bin = min(max(bin, 0), 127);
        float sel = (bin & 1) ? h1 : h0;
        float hb = __shfl(sel, bin >> 1);
        if (lane == 0) acc += hb - lse + 4.8520302639196171f;  // log(128)
    }
    if (lane == 0) atomicAdd(out, -acc);
}

extern "C" void kernel_launch(void* const* d_in, const int* in_sizes, int n_in,
                              void* d_out, int out_size, void* d_ws, size_t ws_size,
                              hipStream_t stream) {
    const float* latent         = (const float*)d_in[0];
    const int*   genes_oi       = (const int*)d_in[1];
    const int*   cells_oi       = (const int*)d_in[2];
    const float* cut_coord      = (const float*)d_in[3];
    const int*   cut_pair       = (const int*)d_in[4];
    const int*   cut_gene       = (const int*)d_in[5];
    const int*   local_cxg      = (const int*)d_in[6];
    const float* logit_weight   = (const float*)d_in[7];
    const float* rho_weight     = (const float*)d_in[8];
    const float* rho_bias       = (const float*)d_in[9];
    const int*   libsize        = (const int*)d_in[10];
    const float* spline_heights = (const float*)d_in[11];
    int G = in_sizes[1];
    int B = in_sizes[2];
    int ncuts = in_sizes[4];

    unsigned int* counts = (unsigned int*)d_ws;
    size_t counts_bytes = (size_t)B * G * sizeof(unsigned int);
    size_t ofs = (counts_bytes + 255) & ~(size_t)255;
    unsigned short* delta = (unsigned short*)((char*)d_ws + ofs);
    size_t avail = ws_size > ofs ? ws_size - ofs : 0;
    size_t per_cell = (size_t)G * CDIM * sizeof(unsigned short);
    size_t cb_fit = avail / per_cell;
    int CB = (int)(cb_fit < (size_t)B ? cb_fit : (size_t)B);
    CB &= ~15;
    if (CB < 16) CB = 16;   // assume ws can hold at least 16 cells (~10 MB)

    float* out = (float*)d_out;
    hipMemsetAsync(out, 0, sizeof(float) * out_size, stream);
    hipMemsetAsync(counts, 0, counts_bytes, stream);

    hist_kernel<<<(ncuts + 255) / 256, 256, 0, stream>>>(local_cxg, ncuts, counts);
    poisson_kernel<<<(B * G + 255) / 256, 256, 0, stream>>>(
        latent, genes_oi, cells_oi, rho_weight, rho_bias, libsize, counts, B, G, out);

    for (int b0 = 0; b0 < B; b0 += CB) {
        int CBc = (B - b0 < CB) ? (B - b0) : CB;
        dim3 grid(G, (CBc + 63) / 64);
        delta_gemm_kernel<<<grid, 256, 0, stream>>>(latent, genes_oi, logit_weight,
                                                    delta, G, b0, CBc);
        mixture_kernel<<<2048, 256, 0, stream>>>(cut_pair, cut_gene, cut_coord, genes_oi,
                                                 spline_heights, delta, b0 * G,
                                                 (b0 + CBc) * G, ncuts, out);
    }
}

// Round 2
// 381.903 us; speedup vs baseline: 1.1579x; 1.1579x over previous
//
#include <hip/hip_runtime.h>
#include <hip/hip_bf16.h>

#define LDIM 64
#define CDIM 128

static __device__ __forceinline__ unsigned short f2bf(float f) {
    unsigned int x = __float_as_uint(f);
    unsigned int r = (x + 0x7fffu + ((x >> 16) & 1u)) >> 16;
    return (unsigned short)r;
}
static __device__ __forceinline__ float bf2f(unsigned int u) {
    return __uint_as_float(u << 16);
}

// ---- counts = bincount(local_cellxgene_ix) ----
__global__ __launch_bounds__(256) void hist_kernel(const int* __restrict__ idx, int n,
                                                   unsigned int* __restrict__ counts) {
    int i = blockIdx.x * blockDim.x + threadIdx.x;
    int stride = gridDim.x * blockDim.x;
    for (; i < n; i += stride) atomicAdd(&counts[idx[i]], 1u);
}

// ---- Poisson part: sum over all (b,g) pairs ----
__global__ __launch_bounds__(256) void poisson_kernel(
    const float* __restrict__ latent, const int* __restrict__ genes_oi,
    const int* __restrict__ cells_oi, const float* __restrict__ rho_weight,
    const float* __restrict__ rho_bias, const int* __restrict__ libsize,
    const unsigned int* __restrict__ counts, int B, int G, float* __restrict__ out) {
    int total = B * G;
    float acc = 0.f;
    for (int i = blockIdx.x * blockDim.x + threadIdx.x; i < total;
         i += gridDim.x * blockDim.x) {
        int b = i / G;
        int g = i - b * G;
        int gene = genes_oi[g];
        const float4* la = (const float4*)(latent + (size_t)b * LDIM);
        const float4* rw = (const float4*)(rho_weight + (size_t)gene * LDIM);
        float d = 0.f;
        #pragma unroll
        for (int k = 0; k < LDIM / 4; ++k) {
            float4 a = la[k], w = rw[k];
            d += a.x * w.x + a.y * w.y + a.z * w.z + a.w * w.w;
        }
        float lib = (float)libsize[cells_oi[b]];
        float rate = rho_bias[gene] * __expf(d) * lib;
        unsigned int c = counts[i];
        float lgam = 0.f;
        for (unsigned int k = 2; k <= c; ++k) lgam += __logf((float)k);
        acc += (float)c * __logf(rate) - rate - lgam;
    }
    #pragma unroll
    for (int o = 32; o; o >>= 1) acc += __shfl_xor(acc, o);
    if ((threadIdx.x & 63) == 0) atomicAdd(out, -acc);
}

// ---- mixture_delta GEMM: per gene, 64-cell tile; stores bf16 chunk ----
__global__ __launch_bounds__(256) void delta_gemm_kernel(
    const float* __restrict__ latent, const int* __restrict__ genes_oi,
    const float* __restrict__ logit_weight, unsigned short* __restrict__ delta,
    int G, int b0, int CBc) {
    __shared__ float lw_s[LDIM][CDIM];       // 32 KB
    __shared__ float lat_s[64][LDIM + 4];    // 17 KB, padded stride (bank spread)
    int g = blockIdx.x;
    int t = threadIdx.x;
    int row0 = blockIdx.y * 64;
    int gene = genes_oi[g];

    // stage logit_weight[gene] (64x128 f32, contiguous) via float4
    const float4* src = (const float4*)(logit_weight + (size_t)gene * LDIM * CDIM);
    float4* dst = (float4*)(&lw_s[0][0]);
    #pragma unroll
    for (int k = 0; k < (LDIM * CDIM / 4) / 256; ++k) dst[t + k * 256] = src[t + k * 256];

    // stage 64 cells of latent (zero-pad beyond chunk)
    for (int idx = t; idx < 64 * (LDIM / 4); idx += 256) {
        int r = idx >> 4;   // LDIM/4 == 16
        int k = idx & 15;
        float4 v = make_float4(0.f, 0.f, 0.f, 0.f);
        if (row0 + r < CBc)
            v = ((const float4*)(latent + (size_t)(b0 + row0 + r) * LDIM))[k];
        ((float4*)(&lat_s[r][0]))[k] = v;
    }
    __syncthreads();

    int cg = t >> 4;   // 16 cell-groups x 4 cells
    int qc = t & 15;   // 16 c-groups x 8 cols
    float acc[4][8];
    #pragma unroll
    for (int i = 0; i < 4; ++i)
        #pragma unroll
        for (int j = 0; j < 8; ++j) acc[i][j] = 0.f;

    #pragma unroll 4
    for (int l = 0; l < LDIM; ++l) {
        const float4* wr = (const float4*)(&lw_s[l][0]);
        float4 w0 = wr[qc * 2];
        float4 w1 = wr[qc * 2 + 1];
        #pragma unroll
        for (int i = 0; i < 4; ++i) {
            float a = lat_s[cg * 4 + i][l];
            acc[i][0] += a * w0.x; acc[i][1] += a * w0.y;
            acc[i][2] += a * w0.z; acc[i][3] += a * w0.w;
            acc[i][4] += a * w1.x; acc[i][5] += a * w1.y;
            acc[i][6] += a * w1.z; acc[i][7] += a * w1.w;
        }
    }

    #pragma unroll
    for (int i = 0; i < 4; ++i) {
        int rloc = row0 + cg * 4 + i;
        if (rloc < CBc) {
            union { unsigned short u[8]; uint4 v; } pk;
            #pragma unroll
            for (int j = 0; j < 8; ++j) pk.u[j] = f2bf(acc[i][j]);
            *((uint4*)(delta + ((size_t)rloc * G + g) * CDIM + qc * 8)) = pk.v;
        }
    }
}

// ---- mixture likelihood: one cut per 16-lane group, 8 bins per lane ----
__global__ __launch_bounds__(256) void mixture_kernel(
    const int* __restrict__ cut_pair, const int* __restrict__ cut_gene,
    const float* __restrict__ cut_coord, const int* __restrict__ genes_oi,
    const float* __restrict__ spline_heights, const unsigned short* __restrict__ delta,
    int p0, int p1, int ncuts, float* __restrict__ out) {
    int sub = threadIdx.x & 15;
    int lane = threadIdx.x & 63;
    int gidx = (blockIdx.x * blockDim.x + threadIdx.x) >> 4;
    int ngroups = (gridDim.x * blockDim.x) >> 4;
    float acc = 0.f;
    for (int cut = gidx; cut < ncuts; cut += ngroups) {
        int p = cut_pair[cut];
        if (p < p0 || p >= p1) continue;   // group-uniform skip (multi-pass mode)
        int gene = genes_oi[cut_gene[cut]];
        uint4 dv = *(const uint4*)(delta + ((size_t)(p - p0) * CDIM) + sub * 8);
        const float4* hp = (const float4*)(spline_heights + (size_t)gene * CDIM + sub * 8);
        float4 ha = hp[0], hb = hp[1];
        float h0 = ha.x + bf2f(dv.x & 0xffffu);
        float h1 = ha.y + bf2f(dv.x >> 16);
        float h2 = ha.z + bf2f(dv.y & 0xffffu);
        float h3 = ha.w + bf2f(dv.y >> 16);
        float h4 = hb.x + bf2f(dv.z & 0xffffu);
        float h5 = hb.y + bf2f(dv.z >> 16);
        float h6 = hb.z + bf2f(dv.w & 0xffffu);
        float h7 = hb.w + bf2f(dv.w >> 16);

        float m = fmaxf(fmaxf(fmaxf(h0, h1), fmaxf(h2, h3)),
                        fmaxf(fmaxf(h4, h5), fmaxf(h6, h7)));
        #pragma unroll
        for (int o = 1; o < 16; o <<= 1) m = fmaxf(m, __shfl_xor(m, o));
        float s = __expf(h0 - m) + __expf(h1 - m) + __expf(h2 - m) + __expf(h3 - m)
                + __expf(h4 - m) + __expf(h5 - m) + __expf(h6 - m) + __expf(h7 - m);
        #pragma unroll
        for (int o = 1; o < 16; o <<= 1) s += __shfl_xor(s, o);
        float lse = m + __logf(s);

        int bin = (int)(cut_coord[cut] * 128.0f);
        bin = min(max(bin, 0), 127);
        int e = bin & 7;
        float sel = h0;
        sel = (e == 1) ? h1 : sel;
        sel = (e == 2) ? h2 : sel;
        sel = (e == 3) ? h3 : sel;
        sel = (e == 4) ? h4 : sel;
        sel = (e == 5) ? h5 : sel;
        sel = (e == 6) ? h6 : sel;
        sel = (e == 7) ? h7 : sel;
        float hsel = __shfl(sel, (lane & 48) | (bin >> 3));
        if (sub == 0) acc += hsel - lse + 4.8520302639196171f;  // log(128)
    }
    #pragma unroll
    for (int o = 32; o; o >>= 1) acc += __shfl_xor(acc, o);
    if (lane == 0) atomicAdd(out, -acc);
}

extern "C" void kernel_launch(void* const* d_in, const int* in_sizes, int n_in,
                              void* d_out, int out_size, void* d_ws, size_t ws_size,
                              hipStream_t stream) {
    const float* latent         = (const float*)d_in[0];
    const int*   genes_oi       = (const int*)d_in[1];
    const int*   cells_oi       = (const int*)d_in[2];
    const float* cut_coord      = (const float*)d_in[3];
    const int*   cut_pair       = (const int*)d_in[4];
    const int*   cut_gene       = (const int*)d_in[5];
    const int*   local_cxg      = (const int*)d_in[6];
    const float* logit_weight   = (const float*)d_in[7];
    const float* rho_weight     = (const float*)d_in[8];
    const float* rho_bias       = (const float*)d_in[9];
    const int*   libsize        = (const int*)d_in[10];
    const float* spline_heights = (const float*)d_in[11];
    int G = in_sizes[1];
    int B = in_sizes[2];
    int ncuts = in_sizes[4];

    unsigned int* counts = (unsigned int*)d_ws;
    size_t counts_bytes = (size_t)B * G * sizeof(unsigned int);
    size_t ofs = (counts_bytes + 255) & ~(size_t)255;
    unsigned short* delta = (unsigned short*)((char*)d_ws + ofs);
    size_t avail = ws_size > ofs ? ws_size - ofs : 0;
    size_t per_cell = (size_t)G * CDIM * sizeof(unsigned short);
    size_t cb_fit = avail / per_cell;
    int CB = (int)(cb_fit < (size_t)B ? cb_fit : (size_t)B);
    CB &= ~15;
    if (CB < 16) CB = 16;   // assume ws can hold at least 16 cells (~10 MB)

    float* out = (float*)d_out;
    hipMemsetAsync(out, 0, sizeof(float) * out_size, stream);
    hipMemsetAsync(counts, 0, counts_bytes, stream);

    hist_kernel<<<(ncuts + 255) / 256, 256, 0, stream>>>(local_cxg, ncuts, counts);
    poisson_kernel<<<(B * G + 255) / 256, 256, 0, stream>>>(
        latent, genes_oi, cells_oi, rho_weight, rho_bias, libsize, counts, B, G, out);

    for (int b0 = 0; b0 < B; b0 += CB) {
        int CBc = (B - b0 < CB) ? (B - b0) : CB;
        dim3 grid(G, (CBc + 63) / 64);
        delta_gemm_kernel<<<grid, 256, 0, stream>>>(latent, genes_oi, logit_weight,
                                                    delta, G, b0, CBc);
        mixture_kernel<<<2048, 256, 0, stream>>>(cut_pair, cut_gene, cut_coord, genes_oi,
                                                 spline_heights, delta, b0 * G,
                                                 (b0 + CBc) * G, ncuts, out);
    }
}

// Round 3
// 221.697 us; speedup vs baseline: 1.9947x; 1.7226x over previous
//
#include <hip/hip_runtime.h>
#include <hip/hip_bf16.h>

#define LDIM 64
#define CDIM 128
#define LOG128 4.8520302639196171f
#define SWZ(q) ((q) ^ (((q) >> 3) & 7))

static __device__ __forceinline__ unsigned short f2bf(float f) {
    unsigned int x = __float_as_uint(f);
    unsigned int r = (x + 0x7fffu + ((x >> 16) & 1u)) >> 16;
    return (unsigned short)r;
}
static __device__ __forceinline__ float bf2f(unsigned int u) {
    return __uint_as_float(u << 16);
}

// ---- prep: spline_heights f32 -> bf16 table ----
__global__ __launch_bounds__(256) void heights_bf16_kernel(
    const float* __restrict__ h, unsigned short* __restrict__ hbf, int n) {
    int i = blockIdx.x * blockDim.x + threadIdx.x;
    int stride = gridDim.x * blockDim.x;
    for (; i < n; i += stride) hbf[i] = f2bf(h[i]);
}

// ---- prep: per-cut packed record {pair, gene_global<<7 | bin} ----
__global__ __launch_bounds__(256) void rec_kernel(
    const int* __restrict__ cut_pair, const int* __restrict__ cut_gene,
    const float* __restrict__ coord, const int* __restrict__ genes_oi,
    uint2* __restrict__ rec, int ncuts) {
    int i = blockIdx.x * blockDim.x + threadIdx.x;
    int stride = gridDim.x * blockDim.x;
    for (; i < ncuts; i += stride) {
        int p = cut_pair[i];
        int gg = genes_oi[cut_gene[i]];
        int bin = (int)(coord[i] * 128.0f);
        bin = min(max(bin, 0), 127);
        rec[i] = make_uint2((unsigned)p, ((unsigned)gg << 7) | (unsigned)bin);
    }
}

// ---- counts = bincount(local_cellxgene_ix) ----
__global__ __launch_bounds__(256) void hist_kernel(const int* __restrict__ idx, int n,
                                                   unsigned int* __restrict__ counts) {
    int i = blockIdx.x * blockDim.x + threadIdx.x;
    int stride = gridDim.x * blockDim.x;
    for (; i < n; i += stride) atomicAdd(&counts[idx[i]], 1u);
}

// ---- Poisson part: sum over all (b,g) pairs ----
__global__ __launch_bounds__(256) void poisson_kernel(
    const float* __restrict__ latent, const int* __restrict__ genes_oi,
    const int* __restrict__ cells_oi, const float* __restrict__ rho_weight,
    const float* __restrict__ rho_bias, const int* __restrict__ libsize,
    const unsigned int* __restrict__ counts, int B, int G, float* __restrict__ out) {
    __shared__ float red[4];
    int total = B * G;
    float acc = 0.f;
    for (int i = blockIdx.x * blockDim.x + threadIdx.x; i < total;
         i += gridDim.x * blockDim.x) {
        int b = i / G;
        int g = i - b * G;
        int gene = genes_oi[g];
        const float4* la = (const float4*)(latent + (size_t)b * LDIM);
        const float4* rw = (const float4*)(rho_weight + (size_t)gene * LDIM);
        float d = 0.f;
        #pragma unroll
        for (int k = 0; k < LDIM / 4; ++k) {
            float4 a = la[k], w = rw[k];
            d += a.x * w.x + a.y * w.y + a.z * w.z + a.w * w.w;
        }
        float lib = (float)libsize[cells_oi[b]];
        float rate = rho_bias[gene] * __expf(d) * lib;
        unsigned int c = counts[i];
        float lgam = 0.f;
        for (unsigned int k = 2; k <= c; ++k) lgam += __logf((float)k);
        acc += (float)c * __logf(rate) - rate - lgam;
    }
    #pragma unroll
    for (int o = 32; o; o >>= 1) acc += __shfl_xor(acc, o);
    if ((threadIdx.x & 63) == 0) red[threadIdx.x >> 6] = acc;
    __syncthreads();
    if (threadIdx.x == 0) atomicAdd(out, -(red[0] + red[1] + red[2] + red[3]));
}

// ---- mixture_delta GEMM: 128 cells x 128 cols per block, 8x8 per lane ----
__global__ __launch_bounds__(256) void delta_gemm_kernel(
    const float* __restrict__ latent, const int* __restrict__ genes_oi,
    const float* __restrict__ logit_weight, unsigned short* __restrict__ delta,
    int G, int b0, int CBc) {
    __shared__ float lw_s[LDIM * CDIM];   // 32 KB  [l][swizzled col-quad]
    __shared__ float latT[LDIM * CDIM];   // 32 KB  [l][swizzled cell-quad]
    int g = blockIdx.x;
    int t = threadIdx.x;
    int row0 = blockIdx.y * 128;
    int gene = genes_oi[g];

    // stage logit_weight[gene]: 64 rows x 32 quads, swizzled within row
    const float4* src = (const float4*)(logit_weight + (size_t)gene * LDIM * CDIM);
    #pragma unroll
    for (int k = 0; k < 8; ++k) {
        int fq = t + k * 256;
        int l = fq >> 5, q = fq & 31;
        ((float4*)lw_s)[(l << 5) | SWZ(q)] = src[fq];
    }
    // stage latent transposed: latT[l][cell], swizzled quads
    #pragma unroll
    for (int k = 0; k < 8; ++k) {
        int idx = t + k * 256;       // 128 cells x 16 k-quads
        int cell = idx & 127;
        int kq = idx >> 7;
        float4 v = make_float4(0.f, 0.f, 0.f, 0.f);
        int r = row0 + cell;
        if (r < CBc) v = ((const float4*)(latent + (size_t)(b0 + r) * LDIM))[kq];
        int col = (SWZ(cell >> 2) << 2) | (cell & 3);
        latT[((kq * 4 + 0) << 7) | col] = v.x;
        latT[((kq * 4 + 1) << 7) | col] = v.y;
        latT[((kq * 4 + 2) << 7) | col] = v.z;
        latT[((kq * 4 + 3) << 7) | col] = v.w;
    }
    __syncthreads();

    int cr = t >> 4;   // 16 cell-groups of 8
    int cc = t & 15;   // 16 col-groups of 8
    int aq0 = SWZ(2 * cr), aq1 = SWZ(2 * cr + 1);
    int wq0 = SWZ(2 * cc), wq1 = SWZ(2 * cc + 1);
    float acc[8][8];
    #pragma unroll
    for (int i = 0; i < 8; ++i)
        #pragma unroll
        for (int j = 0; j < 8; ++j) acc[i][j] = 0.f;

    #pragma unroll 4
    for (int l = 0; l < LDIM; ++l) {
        float4 a0 = ((const float4*)latT)[(l << 5) | aq0];
        float4 a1 = ((const float4*)latT)[(l << 5) | aq1];
        float4 w0 = ((const float4*)lw_s)[(l << 5) | wq0];
        float4 w1 = ((const float4*)lw_s)[(l << 5) | wq1];
        float a[8] = {a0.x, a0.y, a0.z, a0.w, a1.x, a1.y, a1.z, a1.w};
        float w[8] = {w0.x, w0.y, w0.z, w0.w, w1.x, w1.y, w1.z, w1.w};
        #pragma unroll
        for (int i = 0; i < 8; ++i)
            #pragma unroll
            for (int j = 0; j < 8; ++j)
                acc[i][j] = fmaf(a[i], w[j], acc[i][j]);
    }

    #pragma unroll
    for (int i = 0; i < 8; ++i) {
        int rloc = row0 + cr * 8 + i;
        if (rloc < CBc) {
            union { unsigned short u[8]; uint4 v; } pk;
            #pragma unroll
            for (int j = 0; j < 8; ++j) pk.u[j] = f2bf(acc[i][j]);
            *((uint4*)(delta + ((size_t)rloc * G + g) * CDIM + cc * 8)) = pk.v;
        }
    }
}

// ---- mixture likelihood: 16-lane group per cut, 2 cuts per iteration ----
static __device__ __forceinline__ float contrib(uint4 dv, uint4 hv, int bin, int lane) {
    float h0 = bf2f(hv.x & 0xffffu) + bf2f(dv.x & 0xffffu);
    float h1 = bf2f(hv.x >> 16)     + bf2f(dv.x >> 16);
    float h2 = bf2f(hv.y & 0xffffu) + bf2f(dv.y & 0xffffu);
    float h3 = bf2f(hv.y >> 16)     + bf2f(dv.y >> 16);
    float h4 = bf2f(hv.z & 0xffffu) + bf2f(dv.z & 0xffffu);
    float h5 = bf2f(hv.z >> 16)     + bf2f(dv.z >> 16);
    float h6 = bf2f(hv.w & 0xffffu) + bf2f(dv.w & 0xffffu);
    float h7 = bf2f(hv.w >> 16)     + bf2f(dv.w >> 16);
    float m = fmaxf(fmaxf(fmaxf(h0, h1), fmaxf(h2, h3)),
                    fmaxf(fmaxf(h4, h5), fmaxf(h6, h7)));
    #pragma unroll
    for (int o = 1; o < 16; o <<= 1) m = fmaxf(m, __shfl_xor(m, o));
    float s = __expf(h0 - m) + __expf(h1 - m) + __expf(h2 - m) + __expf(h3 - m)
            + __expf(h4 - m) + __expf(h5 - m) + __expf(h6 - m) + __expf(h7 - m);
    #pragma unroll
    for (int o = 1; o < 16; o <<= 1) s += __shfl_xor(s, o);
    int e = bin & 7;
    float sel = h0;
    sel = (e == 1) ? h1 : sel;
    sel = (e == 2) ? h2 : sel;
    sel = (e == 3) ? h3 : sel;
    sel = (e == 4) ? h4 : sel;
    sel = (e == 5) ? h5 : sel;
    sel = (e == 6) ? h6 : sel;
    sel = (e == 7) ? h7 : sel;
    float hsel = __shfl(sel, (lane & 48) | (bin >> 3));
    return hsel - (m + __logf(s)) + LOG128;
}

__global__ __launch_bounds__(256) void mixture_kernel(
    const uint2* __restrict__ rec, const unsigned short* __restrict__ hbf,
    const unsigned short* __restrict__ delta, int lo, int hi, int ncuts,
    float* __restrict__ out) {
    __shared__ float red[4];
    int t = threadIdx.x;
    int sub = t & 15;
    int lane = t & 63;
    int gid = (blockIdx.x * blockDim.x + t) >> 4;
    int ngr = (gridDim.x * blockDim.x) >> 4;
    float acc = 0.f;
    for (int base = gid * 2; base < ncuts; base += ngr * 2) {
        uint2 r0 = rec[base];
        int ok1 = (base + 1 < ncuts);
        uint2 r1 = rec[ok1 ? base + 1 : base];
        int p0 = (int)r0.x, p1 = (int)r1.x;
        int v0 = (p0 >= lo) & (p0 < hi);
        int v1 = ok1 & (p1 >= lo) & (p1 < hi);
        size_t da0 = v0 ? ((size_t)(p0 - lo) << 7) : 0;
        size_t da1 = v1 ? ((size_t)(p1 - lo) << 7) : 0;
        uint4 dv0 = *(const uint4*)(delta + da0 + sub * 8);
        uint4 hv0 = *(const uint4*)(hbf + ((size_t)(r0.y >> 7) << 7) + sub * 8);
        uint4 dv1 = *(const uint4*)(delta + da1 + sub * 8);
        uint4 hv1 = *(const uint4*)(hbf + ((size_t)(r1.y >> 7) << 7) + sub * 8);
        float c0 = contrib(dv0, hv0, (int)(r0.y & 127u), lane);
        float c1 = contrib(dv1, hv1, (int)(r1.y & 127u), lane);
        if (sub == 0) acc += (v0 ? c0 : 0.f) + (v1 ? c1 : 0.f);
    }
    #pragma unroll
    for (int o = 32; o; o >>= 1) acc += __shfl_xor(acc, o);
    if (lane == 0) red[t >> 6] = acc;
    __syncthreads();
    if (t == 0) atomicAdd(out, -(red[0] + red[1] + red[2] + red[3]));
}

extern "C" void kernel_launch(void* const* d_in, const int* in_sizes, int n_in,
                              void* d_out, int out_size, void* d_ws, size_t ws_size,
                              hipStream_t stream) {
    const float* latent         = (const float*)d_in[0];
    const int*   genes_oi       = (const int*)d_in[1];
    const int*   cells_oi       = (const int*)d_in[2];
    const float* cut_coord      = (const float*)d_in[3];
    const int*   cut_pair       = (const int*)d_in[4];
    const int*   cut_gene       = (const int*)d_in[5];
    const int*   local_cxg      = (const int*)d_in[6];
    const float* logit_weight   = (const float*)d_in[7];
    const float* rho_weight     = (const float*)d_in[8];
    const float* rho_bias       = (const float*)d_in[9];
    const int*   libsize        = (const int*)d_in[10];
    const float* spline_heights = (const float*)d_in[11];
    int G = in_sizes[1];
    int B = in_sizes[2];
    int ncuts = in_sizes[4];
    int nheights = in_sizes[11];   // n_genes_total * 128

    // workspace layout
    char* ws = (char*)d_ws;
    size_t off = 0;
    unsigned int* counts = (unsigned int*)(ws + off);
    off += ((size_t)B * G * 4 + 255) & ~(size_t)255;
    uint2* rec = (uint2*)(ws + off);
    off += ((size_t)ncuts * 8 + 255) & ~(size_t)255;
    unsigned short* hbf = (unsigned short*)(ws + off);
    off += ((size_t)nheights * 2 + 255) & ~(size_t)255;
    unsigned short* delta = (unsigned short*)(ws + off);
    size_t avail = ws_size > off ? ws_size - off : 0;
    size_t per_cell = (size_t)G * CDIM * sizeof(unsigned short);
    size_t cb_fit = avail / per_cell;
    int CB = (int)(cb_fit < (size_t)B ? cb_fit : (size_t)B);
    CB &= ~15;
    if (CB < 16) CB = 16;

    float* out = (float*)d_out;
    hipMemsetAsync(out, 0, sizeof(float) * out_size, stream);
    hipMemsetAsync(counts, 0, (size_t)B * G * 4, stream);

    heights_bf16_kernel<<<(nheights + 255) / 256, 256, 0, stream>>>(
        spline_heights, hbf, nheights);
    rec_kernel<<<(ncuts + 255) / 256, 256, 0, stream>>>(
        cut_pair, cut_gene, cut_coord, genes_oi, rec, ncuts);
    hist_kernel<<<(ncuts + 255) / 256, 256, 0, stream>>>(local_cxg, ncuts, counts);
    poisson_kernel<<<2000, 256, 0, stream>>>(
        latent, genes_oi, cells_oi, rho_weight, rho_bias, libsize, counts, B, G, out);

    for (int b0 = 0; b0 < B; b0 += CB) {
        int CBc = (B - b0 < CB) ? (B - b0) : CB;
        dim3 grid(G, (CBc + 127) / 128);
        delta_gemm_kernel<<<grid, 256, 0, stream>>>(latent, genes_oi, logit_weight,
                                                    delta, G, b0, CBc);
        mixture_kernel<<<2048, 256, 0, stream>>>(rec, hbf, delta, b0 * G,
                                                 (b0 + CBc) * G, ncuts, out);
    }
}